// Round 10
// baseline (644.344 us; speedup 1.0000x reference)
//
#include <hip/hip_runtime.h>
#include <stdint.h>

// Problem constants
#define Bb  8
#define Ss  4096
#define Dd  512
#define DIi 2048
#define Mm  (Bb*Ss)   // 32768 rows

typedef unsigned short u16;
typedef __bf16 bf16x8 __attribute__((ext_vector_type(8)));
typedef float  f32x4  __attribute__((ext_vector_type(4)));

__device__ __forceinline__ float bfu(unsigned int u) {
  return __uint_as_float((u & 0xffffu) << 16);
}
__device__ __forceinline__ u16 f2bu(float f) {
  unsigned int x = __float_as_uint(f);
  return (u16)((x + 0x7fffu + ((x >> 16) & 1u)) >> 16);  // RNE
}

// ================= fused prep: zero + f32->bf16 conv + 6 transposes =================
__device__ __forceinline__ void tr_tile(const float* __restrict__ W, u16* __restrict__ Wt,
                                        int K, int N, int local, int tid) {
  __shared__ float t[32][33];
  const int nx = N / 32;
  const int n0 = (local % nx) * 32, k0 = (local / nx) * 32;
  const int tx = tid & 31, ty = tid >> 5;   // 32 x 8
#pragma unroll
  for (int i = 0; i < 32; i += 8)
    t[ty + i][tx] = W[(long)(k0 + ty + i) * N + n0 + tx];
  __syncthreads();
#pragma unroll
  for (int i = 0; i < 32; i += 8)
    Wt[(long)(n0 + ty + i) * K + k0 + tx] = f2bu(t[tx][ty + i]);
}

__global__ __launch_bounds__(256) void prep(
    const float* __restrict__ x, u16* __restrict__ xb,
    const float* wk, const float* wq, const float* wv, const float* w1,
    const float* wo, const float* w2,
    u16* wkT, u16* wqT, u16* wvT, u16* w1T, u16* woT, u16* w2T,
    float* __restrict__ zptr) {
  const int bid = blockIdx.x, tid = threadIdx.x;
  if (bid < 320) {                       // zero 81920 floats (nksq,nqsq,kvp)
    zptr[bid * 256 + tid] = 0.f;
  } else if (bid < 2368) {               // conv x -> xb
    long i = (long)(bid - 320) * 256 + tid;
    const long n4 = (long)Mm * Dd / 4;
    const long st = 2048L * 256;
    for (; i < n4; i += st) {
      float4 v = ((const float4*)x)[i];
      ushort4 o;
      o.x = f2bu(v.x); o.y = f2bu(v.y); o.z = f2bu(v.z); o.w = f2bu(v.w);
      ((ushort4*)xb)[i] = o;
    }
  } else if (bid < 3392)  tr_tile(wk, wkT, Dd, DIi, bid - 2368, tid);
  else if (bid < 4416)    tr_tile(wq, wqT, Dd, DIi, bid - 3392, tid);
  else if (bid < 5440)    tr_tile(wv, wvT, Dd, DIi, bid - 4416, tid);
  else if (bid < 6464)    tr_tile(w1, w1T, Dd, DIi, bid - 5440, tid);
  else if (bid < 7488)    tr_tile(wo, woT, DIi, Dd, bid - 6464, tid);
  else                    tr_tile(w2, w2T, DIi, Dd, bid - 7488, tid);
}

// wob[b][n][k] = woT[n][k] * kv[b][k]
__global__ __launch_bounds__(256) void build_wob(const u16* __restrict__ woT,
                                                 const float* __restrict__ kv,
                                                 u16* __restrict__ wob) {
  const int b = blockIdx.y;
  long i = (long)blockIdx.x * 256 + threadIdx.x;
  const long tot = (long)Dd * DIi / 8;
  if (i >= tot) return;
  const long e = i * 8;
  const int k = (int)(e & (DIi - 1));
  ushort4 w0 = *(const ushort4*)(woT + e);
  ushort4 w1 = *(const ushort4*)(woT + e + 4);
  const float* kvp = kv + (long)b * DIi + k;
  ushort4 o0, o1;
  o0.x = f2bu(bfu(w0.x) * kvp[0]); o0.y = f2bu(bfu(w0.y) * kvp[1]);
  o0.z = f2bu(bfu(w0.z) * kvp[2]); o0.w = f2bu(bfu(w0.w) * kvp[3]);
  o1.x = f2bu(bfu(w1.x) * kvp[4]); o1.y = f2bu(bfu(w1.y) * kvp[5]);
  o1.z = f2bu(bfu(w1.z) * kvp[6]); o1.w = f2bu(bfu(w1.w) * kvp[7]);
  u16* dst = wob + (long)b * Dd * DIi + e;
  *(ushort4*)dst = o0;
  *(ushort4*)(dst + 4) = o1;
}

#define GLL(src, dst) \
  __builtin_amdgcn_global_load_lds((const __attribute__((address_space(1))) unsigned int*)(src), \
                                   (__attribute__((address_space(3))) unsigned int*)(dst), 16, 0, 0)

// ========== 128^2-tile 4-wave GEMM (round-3 proven structure, K=512 ops) ==========
// MP_PROJ: dual-target K/Q — row-half selects {Bt->Ybf,nsq} vs {Bt2->Ybf2,nsq2}
// MP_FFN1: bf16 Y = relu(acc + bias[col])
#define BM 128
#define BN 128
#define BK 32
enum { MP_PROJ = 0, MP_FFN1 = 1 };

template<int MODE>
__global__ __launch_bounds__(256) void mega128(
    const u16* __restrict__ A, const u16* __restrict__ Bt, const u16* __restrict__ Bt2,
    int N, int K,
    u16* __restrict__ Ybf, u16* __restrict__ Ybf2,
    const float* __restrict__ bias,
    float* __restrict__ nsq, float* __restrict__ nsq2, int yoff)
{
  __shared__ u16 As[BM * BK];   // 8 KB
  __shared__ u16 Bs[BN * BK];   // 8 KB

  const int tid  = threadIdx.x;
  const int lane = tid & 63;
  const int w    = tid >> 6;
  const int wr = w >> 1, wc = w & 1;          // 2x2 wave grid, 64x64 per wave
  const int l15 = lane & 15, lg = lane >> 4;

  const long bm0l = (long)(blockIdx.y + yoff) * BM;
  const bool isQ = (MODE == MP_PROJ) && (bm0l >= Mm);
  const long bm0 = isQ ? (bm0l - Mm) : bm0l;
  const long bn0 = (long)blockIdx.x * BN;
  const u16* Bsel = isQ ? Bt2 : Bt;

  const int c0 = tid, c1 = tid + 256;
  const u16* aS0 = A    + (bm0 + (c0 >> 2)) * K + (c0 & 3) * 8;
  const u16* aS1 = A    + (bm0 + (c1 >> 2)) * K + (c1 & 3) * 8;
  const u16* bS0 = Bsel + (bn0 + (c0 >> 2)) * K + (c0 & 3) * 8;
  const u16* bS1 = Bsel + (bn0 + (c1 >> 2)) * K + (c1 & 3) * 8;
  u16* aD0 = As + w * 512;          // wave-uniform LDS bases (HW adds lane*16B)
  u16* aD1 = As + 2048 + w * 512;
  u16* bD0 = Bs + w * 512;
  u16* bD1 = Bs + 2048 + w * 512;

  f32x4 acc[4][4] = {};

  for (int k0 = 0; k0 < K; k0 += BK) {
    GLL(aS0 + k0, aD0);
    GLL(aS1 + k0, aD1);
    GLL(bS0 + k0, bD0);
    GLL(bS1 + k0, bD1);
    __syncthreads();   // drains vmcnt for staging, then barrier

    bf16x8 af[4], bfv[4];
#pragma unroll
    for (int m = 0; m < 4; ++m)
      af[m] = *(const bf16x8*)(As + (wr * 64 + m * 16 + l15) * BK + lg * 8);
#pragma unroll
    for (int n = 0; n < 4; ++n)
      bfv[n] = *(const bf16x8*)(Bs + (wc * 64 + n * 16 + l15) * BK + lg * 8);
#pragma unroll
    for (int m = 0; m < 4; ++m)
#pragma unroll
      for (int n = 0; n < 4; ++n)
        acc[m][n] = __builtin_amdgcn_mfma_f32_16x16x32_bf16(af[m], bfv[n], acc[m][n], 0, 0, 0);
    __syncthreads();   // LDS reads done before next stage overwrites
  }

  if constexpr (MODE == MP_PROJ) {
    u16* Yo   = isQ ? Ybf2 : Ybf;
    float* ns = isQ ? nsq2 : nsq;
    float sk[16];
#pragma unroll
    for (int i = 0; i < 16; ++i) sk[i] = 0.f;
#pragma unroll
    for (int m = 0; m < 4; ++m) {
      const long row0 = bm0 + wr * 64 + m * 16 + lg * 4;
#pragma unroll
      for (int n = 0; n < 4; ++n) {
        const long col = bn0 + wc * 64 + n * 16 + l15;
#pragma unroll
        for (int r = 0; r < 4; ++r) {
          const float v = acc[m][n][r];
          Yo[(row0 + r) * N + col] = f2bu(v);
          sk[m * 4 + r] += v * v;
        }
      }
    }
#pragma unroll
    for (int i = 0; i < 16; ++i) {
#pragma unroll
      for (int off = 1; off < 16; off <<= 1)
        sk[i] += __shfl_xor(sk[i], off, 64);
    }
    if (l15 == 0) {
#pragma unroll
      for (int m = 0; m < 4; ++m)
#pragma unroll
        for (int r = 0; r < 4; ++r)
          atomicAdd(&ns[bm0 + wr * 64 + m * 16 + lg * 4 + r], sk[m * 4 + r]);
    }
  } else {  // MP_FFN1
#pragma unroll
    for (int m = 0; m < 4; ++m) {
      const long row0 = bm0 + wr * 64 + m * 16 + lg * 4;
#pragma unroll
      for (int n = 0; n < 4; ++n) {
        const long col = bn0 + wc * 64 + n * 16 + l15;
#pragma unroll
        for (int r = 0; r < 4; ++r) {
          float o = acc[m][n][r] + bias[col];
          o = o > 0.f ? o : 0.f;
          Ybf[(row0 + r) * N + col] = f2bu(o);
        }
      }
    }
  }
}

// =================== 256^2-tile 8-wave pipelined GEMM (K=2048 ops + G_KV) ===================
enum { G_WO = 1, G_FFN2 = 3, G_KV = 4 };

template<int MODE>
__global__ __launch_bounds__(512, 2) void gemm8(
    const u16* __restrict__ A, const u16* __restrict__ Bt,
    int N, int K,
    u16* __restrict__ Ybf, float* __restrict__ Yf,
    const u16* __restrict__ resb, const float* __restrict__ bias,
    const float* __restrict__ nsqIn,
    const u16* __restrict__ Kst, float* __restrict__ kvout)
{
  __shared__ u16 lds8[65536];   // 128 KB

  const int bx = blockIdx.x;
  const int by = blockIdx.y;
  const int tid  = threadIdx.x;
  const int lane = tid & 63;
  const int wid  = tid >> 6;
  const int wr = wid >> 2, wc = wid & 3;
  const int l15 = lane & 15, lg = lane >> 4;

  const long bm0 = (long)by * 256;
  const long bn0 = (long)bx * 256;
  const int NT = K >> 6;

  const int bq = (int)(bm0 >> 12);
  const u16* pA = A + bm0 * K;
  const u16* pB = Bt + bn0 * K + (MODE == G_WO ? (size_t)bq * Dd * DIi : 0);

  const int rowT = ((tid >> 6) << 3) | (tid & 7);
  const int cc8  = ((tid >> 3) & 7) * 8;

#define STAGE(PTR, LD, H, TT, BUFU, REGU) do {                                  \
    const u16* s0_ = (PTR) + (size_t)((H) * 128 + rowT) * (LD)                  \
                     + (size_t)(TT) * 64 + cc8;                                 \
    u16* d_ = lds8 + (BUFU) + (REGU) + (H) * 8192 + wid * 512;                  \
    GLL(s0_, d_);                                                               \
    GLL(s0_ + (size_t)64 * (LD), d_ + 4096);                                    \
  } while (0)

  const int aoff = (wr * 16384 + (l15 >> 3) * 1024 + lg * 128 + (l15 & 7) * 16) >> 1;
  const int boff = (32768 + (wc >> 1) * 16384 + (wc & 1) * 8192 +
                    (l15 >> 3) * 1024 + lg * 128 + (l15 & 7) * 16) >> 1;
#define LDA(M_, KS_, BU_) (*(const bf16x8*)(lds8 + (BU_) + aoff + (M_) * 1024 + (KS_) * 256))
#define LDB(N_, KS_, BU_) (*(const bf16x8*)(lds8 + (BU_) + boff + (N_) * 1024 + (KS_) * 256))

  f32x4 acc[8][4] = {};

  STAGE(pA, K, 0, 0, 0, 0);
  STAGE(pA, K, 1, 0, 0, 0);
  STAGE(pB, K, 0, 0, 0, 16384);
  STAGE(pB, K, 1, 0, 0, 16384);
  STAGE(pA, K, 0, 1, 32768, 0);
  asm volatile("s_waitcnt vmcnt(2)" ::: "memory");
  __builtin_amdgcn_s_barrier();

  for (int t = 0; t < NT; ++t) {
    const int bufu = (t & 1) * 32768;
    const int nbuf = bufu ^ 32768;
    bf16x8 aF[4], bF[4];

#pragma unroll
    for (int n = 0; n < 4; ++n) bF[n] = LDB(n, 0, bufu);
#pragma unroll
    for (int m = 0; m < 4; ++m) aF[m] = LDA(m, 0, bufu);
    if (t + 1 < NT) STAGE(pA, K, 1, t + 1, nbuf, 0);
    __builtin_amdgcn_s_barrier();
    __builtin_amdgcn_s_setprio(1);
#pragma unroll
    for (int m = 0; m < 4; ++m)
#pragma unroll
      for (int n = 0; n < 4; ++n)
        acc[m][n] = __builtin_amdgcn_mfma_f32_16x16x32_bf16(aF[m], bF[n], acc[m][n], 0, 0, 0);
    __builtin_amdgcn_s_setprio(0);

#pragma unroll
    for (int m = 0; m < 4; ++m) aF[m] = LDA(4 + m, 0, bufu);
    if (t + 1 < NT) STAGE(pB, K, 0, t + 1, nbuf, 16384);
    __builtin_amdgcn_s_barrier();
    __builtin_amdgcn_s_setprio(1);
#pragma unroll
    for (int m = 0; m < 4; ++m)
#pragma unroll
      for (int n = 0; n < 4; ++n)
        acc[4 + m][n] = __builtin_amdgcn_mfma_f32_16x16x32_bf16(aF[m], bF[n], acc[4 + m][n], 0, 0, 0);
    __builtin_amdgcn_s_setprio(0);

#pragma unroll
    for (int n = 0; n < 4; ++n) bF[n] = LDB(n, 1, bufu);
#pragma unroll
    for (int m = 0; m < 4; ++m) aF[m] = LDA(m, 1, bufu);
    if (t + 1 < NT) STAGE(pB, K, 1, t + 1, nbuf, 16384);
    __builtin_amdgcn_s_barrier();
    __builtin_amdgcn_s_setprio(1);
#pragma unroll
    for (int m = 0; m < 4; ++m)
#pragma unroll
      for (int n = 0; n < 4; ++n)
        acc[m][n] = __builtin_amdgcn_mfma_f32_16x16x32_bf16(aF[m], bF[n], acc[m][n], 0, 0, 0);
    __builtin_amdgcn_s_setprio(0);

#pragma unroll
    for (int m = 0; m < 4; ++m) aF[m] = LDA(4 + m, 1, bufu);
    __builtin_amdgcn_s_barrier();
    __builtin_amdgcn_s_setprio(1);
#pragma unroll
    for (int m = 0; m < 4; ++m)
#pragma unroll
      for (int n = 0; n < 4; ++n)
        acc[4 + m][n] = __builtin_amdgcn_mfma_f32_16x16x32_bf16(aF[m], bF[n], acc[4 + m][n], 0, 0, 0);
    __builtin_amdgcn_s_setprio(0);

    if (t + 1 < NT) {
      __builtin_amdgcn_s_barrier();
      if (t + 2 < NT) {
        STAGE(pA, K, 0, t + 2, bufu, 0);
        asm volatile("s_waitcnt vmcnt(2)" ::: "memory");
      } else {
        asm volatile("s_waitcnt vmcnt(0)" ::: "memory");
      }
      __builtin_amdgcn_s_barrier();
    }
  }

  // =================== epilogue ===================
  if constexpr (MODE == G_KV) {
    __syncthreads();
#pragma unroll
    for (int i = 0; i < 16; ++i) {
      const int r_ = i * 16 + wid * 2 + (lane >> 5);
      const int c_ = (lane & 31) ^ (r_ & 15);
      const u16* src = Kst + (size_t)(bm0 + r_) * N + bn0 + c_ * 8;
      u16* d_ = lds8 + i * 4096 + wid * 512;
      GLL(src, d_);
    }
    asm volatile("s_waitcnt vmcnt(0)" ::: "memory");
    __builtin_amdgcn_s_barrier();

    const int col4 = wc * 64 + l15;
    float cs[4] = {0.f, 0.f, 0.f, 0.f};
#pragma unroll
    for (int m = 0; m < 8; ++m) {
      const long row0g = bm0 + wr * 128 + m * 16 + lg * 4;
      float rn4[4];
#pragma unroll
      for (int r = 0; r < 4; ++r)
        rn4[r] = 1.f / fmaxf(sqrtf(nsqIn[row0g + r]), 1e-12f);
#pragma unroll
      for (int n = 0; n < 4; ++n) {
        const int col = col4 + n * 16;
#pragma unroll
        for (int r = 0; r < 4; ++r) {
          const int krow = wr * 128 + m * 16 + lg * 4 + r;
          const int byte_ = krow * 512 + (((col >> 3) ^ (krow & 15)) << 4) + (col & 7) * 2;
          const float kvl = bfu(*(const u16*)((const char*)lds8 + byte_));
          cs[n] += kvl * rn4[r] * acc[m][n][r];
        }
      }
    }
#pragma unroll
    for (int n = 0; n < 4; ++n) {
      cs[n] += __shfl_xor(cs[n], 16, 64);
      cs[n] += __shfl_xor(cs[n], 32, 64);
    }
    if (lane < 16) {
#pragma unroll
      for (int n = 0; n < 4; ++n) {
        const long col = bn0 + wc * 64 + n * 16 + l15;
        atomicAdd(&kvout[(long)bq * DIi + col], cs[n]);
      }
    }
  } else {
#pragma unroll
    for (int m = 0; m < 8; ++m) {
      const long row0 = bm0 + wr * 128 + m * 16 + lg * 4;
      float rq[4];
      if constexpr (MODE == G_WO) {
#pragma unroll
        for (int r = 0; r < 4; ++r)
          rq[r] = 1.f / fmaxf(sqrtf(nsqIn[row0 + r]), 1e-12f);
      }
#pragma unroll
      for (int n = 0; n < 4; ++n) {
        const long col = bn0 + wc * 64 + n * 16 + l15;
#pragma unroll
        for (int r = 0; r < 4; ++r) {
          const long idx = (row0 + r) * N + col;
          const float v = acc[m][n][r];
          if constexpr (MODE == G_WO) {
            Ybf[idx] = f2bu(v * rq[r] + bfu(resb[idx]));   // resb == Ybf, same idx
          } else {  // G_FFN2
            Yf[idx] = v + bias[col] + bfu(resb[idx]);
          }
        }
      }
    }
  }
#undef STAGE
#undef LDA
#undef LDB
}

extern "C" void kernel_launch(void* const* d_in, const int* in_sizes, int n_in,
                              void* d_out, int out_size, void* d_ws, size_t ws_size,
                              hipStream_t stream) {
  const float* x  = (const float*)d_in[0];
  const float* wq = (const float*)d_in[1];
  const float* wk = (const float*)d_in[2];
  const float* wv = (const float*)d_in[3];
  const float* wo = (const float*)d_in[4];
  const float* w1 = (const float*)d_in[5];
  const float* b1 = (const float*)d_in[6];
  const float* w2 = (const float*)d_in[7];
  const float* b2 = (const float*)d_in[8];
  float* out = (float*)d_out;

  char* p = (char*)d_ws;
  auto take = [&](size_t bytes) {
    char* r = p; p += (bytes + 255) & ~(size_t)255; return r;
  };
  u16*   xb   = (u16*)take((size_t)Mm * Dd * 2);        // x bf16; later attn bf16
  u16*   wkT  = (u16*)take((size_t)DIi * Dd * 2);
  u16*   wqT  = (u16*)take((size_t)DIi * Dd * 2);
  u16*   wvT  = (u16*)take((size_t)DIi * Dd * 2);
  u16*   woT  = (u16*)take((size_t)Dd * DIi * 2);
  u16*   w1T  = (u16*)take((size_t)DIi * Dd * 2);
  u16*   w2T  = (u16*)take((size_t)Dd * DIi * 2);
  u16*   wob  = (u16*)take((size_t)Bb * Dd * DIi * 2);  // 16.8 MB
  u16*   buf1 = (u16*)take((size_t)Mm * DIi * 2);       // K (or K then Q), then h
  float* nksq = (float*)take((size_t)Mm * 4);           // contiguous with next two
  float* nqsq = (float*)take((size_t)Mm * 4);
  float* kvp  = (float*)take((size_t)Bb * DIi * 4);
  const size_t base_used = (size_t)(p - (char*)d_ws);
  const bool par = (ws_size >= base_used + (size_t)Mm * DIi * 2 + 4096);
  u16* bufQ = par ? (u16*)take((size_t)Mm * DIi * 2) : buf1;
  (void)in_sizes; (void)n_in; (void)out_size;

  // fused prep: zero(nksq..kvp) + conv + 6 transposes
  prep<<<8512, 256, 0, stream>>>(x, xb, wk, wq, wv, w1, wo, w2,
                                 wkT, wqT, wvT, w1T, woT, w2T, nksq);

  if (par) {
    // K->buf1 and Q->bufQ in ONE 128^2 dispatch (independent, both read xb)
    mega128<MP_PROJ><<<dim3(DIi / BN, 2 * Mm / BM), 256, 0, stream>>>(
        xb, wkT, wqT, DIi, Dd, buf1, bufQ, nullptr, nksq, nqsq, 0);
  } else {
    mega128<MP_PROJ><<<dim3(DIi / BN, Mm / BM), 256, 0, stream>>>(
        xb, wkT, wqT, DIi, Dd, buf1, nullptr, nullptr, nksq, nullptr, 0);
  }

  // kv[b,e]: V = x@wv tiles + LDS-staged K re-read + 1/||k||  (K dead after)
  gemm8<G_KV><<<dim3(DIi / 256, Mm / 256), 512, 0, stream>>>(
      xb, wvT, DIi, Dd, nullptr, nullptr, nullptr, nullptr, nksq, buf1, kvp);

  if (!par) {
    // sequential fallback: Q -> buf1 (K dead) + nqsq
    mega128<MP_PROJ><<<dim3(DIi / BN, Mm / BM), 256, 0, stream>>>(
        xb, wkT, wqT, DIi, Dd, nullptr, buf1, nullptr, nullptr, nqsq, Mm / BM);
  }

  // wob[b] = woT * kv[b]
  build_wob<<<dim3((Dd * DIi / 8 + 255) / 256, Bb), 256, 0, stream>>>(woT, kvp, wob);

  // attn = (q @ wob[b]) * rsqrt(nqsq) + xb -> bf16 in place of xb
  gemm8<G_WO><<<dim3(Dd / 256, Mm / 256), 512, 0, stream>>>(
      bufQ, wob, Dd, DIi, xb, nullptr, xb, nullptr, nqsq, nullptr, nullptr);

  // h = relu(attn @ w1 + b1) -> buf1 (128^2 structure, K=512)
  mega128<MP_FFN1><<<dim3(DIi / BN, Mm / BM), 256, 0, stream>>>(
      xb, w1T, nullptr, DIi, Dd, buf1, nullptr, b1, nullptr, nullptr, 0);

  // out = h @ w2 + b2 + attn
  gemm8<G_FFN2><<<dim3(Dd / 256, Mm / 256), 512, 0, stream>>>(
      buf1, w2T, Dd, DIi, nullptr, out, xb, b2, nullptr, nullptr, nullptr);
}

// Round 11
// 547.468 us; speedup vs baseline: 1.1770x; 1.1770x over previous
//
#include <hip/hip_runtime.h>
#include <stdint.h>

// Problem constants
#define Bb  8
#define Ss  4096
#define Dd  512
#define DIi 2048
#define Mm  (Bb*Ss)   // 32768 rows

typedef unsigned short u16;
typedef __bf16 bf16x8 __attribute__((ext_vector_type(8)));
typedef float  f32x4  __attribute__((ext_vector_type(4)));

__device__ __forceinline__ float bfu(unsigned int u) {
  return __uint_as_float((u & 0xffffu) << 16);
}
__device__ __forceinline__ u16 f2bu(float f) {
  unsigned int x = __float_as_uint(f);
  return (u16)((x + 0x7fffu + ((x >> 16) & 1u)) >> 16);  // RNE
}

// ================= fused prep: zero + conversions + 5 transposes =================
__device__ __forceinline__ void tr_tile(const float* __restrict__ W, u16* __restrict__ Wt,
                                        int K, int N, int local, int tid) {
  __shared__ float t[32][33];
  const int nx = N / 32;
  const int n0 = (local % nx) * 32, k0 = (local / nx) * 32;
  const int tx = tid & 31, ty = tid >> 5;   // 32 x 8
#pragma unroll
  for (int i = 0; i < 32; i += 8)
    t[ty + i][tx] = W[(long)(k0 + ty + i) * N + n0 + tx];
  __syncthreads();
#pragma unroll
  for (int i = 0; i < 32; i += 8)
    Wt[(long)(n0 + ty + i) * K + k0 + tx] = f2bu(t[tx][ty + i]);
}

__global__ __launch_bounds__(256) void prep(
    const float* __restrict__ x, u16* __restrict__ xb,
    const float* wk, const float* wv, const float* w1,
    const float* wo, const float* w2, const float* wq,
    u16* wkT, u16* wvT, u16* w1T, u16* woT, u16* w2T, u16* wqb,
    float* __restrict__ zptr) {
  const int bid = blockIdx.x, tid = threadIdx.x;
  if (bid < 320) {                       // zero 81920 floats (nksq,nqsq,kvp)
    zptr[bid * 256 + tid] = 0.f;
  } else if (bid < 2368) {               // conv x -> xb (grid-stride)
    long i = (long)(bid - 320) * 256 + tid;
    const long n4 = (long)Mm * Dd / 4;
    const long st = 2048L * 256;
    for (; i < n4; i += st) {
      float4 v = ((const float4*)x)[i];
      ushort4 o;
      o.x = f2bu(v.x); o.y = f2bu(v.y); o.z = f2bu(v.z); o.w = f2bu(v.w);
      ((ushort4*)xb)[i] = o;
    }
  } else if (bid < 3392)  tr_tile(wk, wkT, Dd, DIi, bid - 2368, tid);
  else if (bid < 4416)    tr_tile(wv, wvT, Dd, DIi, bid - 3392, tid);
  else if (bid < 5440)    tr_tile(w1, w1T, Dd, DIi, bid - 4416, tid);
  else if (bid < 6464)    tr_tile(wo, woT, DIi, Dd, bid - 5440, tid);
  else if (bid < 7488)    tr_tile(w2, w2T, DIi, Dd, bid - 6464, tid);
  else {                                 // conv wq -> wqb ([512][2048] bf16)
    long i = (long)(bid - 7488) * 256 + tid;   // 262144 float4 exactly
    float4 v = ((const float4*)wq)[i];
    ushort4 o;
    o.x = f2bu(v.x); o.y = f2bu(v.y); o.z = f2bu(v.z); o.w = f2bu(v.w);
    ((ushort4*)wqb)[i] = o;
  }
}

// wob[b][n][k] = woT[n][k] * kv[b][k]
__global__ __launch_bounds__(256) void build_wob(const u16* __restrict__ woT,
                                                 const float* __restrict__ kv,
                                                 u16* __restrict__ wob) {
  const int b = blockIdx.y;
  long i = (long)blockIdx.x * 256 + threadIdx.x;
  const long tot = (long)Dd * DIi / 8;
  if (i >= tot) return;
  const long e = i * 8;
  const int k = (int)(e & (DIi - 1));
  ushort4 w0 = *(const ushort4*)(woT + e);
  ushort4 w1 = *(const ushort4*)(woT + e + 4);
  const float* kvp = kv + (long)b * DIi + k;
  ushort4 o0, o1;
  o0.x = f2bu(bfu(w0.x) * kvp[0]); o0.y = f2bu(bfu(w0.y) * kvp[1]);
  o0.z = f2bu(bfu(w0.z) * kvp[2]); o0.w = f2bu(bfu(w0.w) * kvp[3]);
  o1.x = f2bu(bfu(w1.x) * kvp[4]); o1.y = f2bu(bfu(w1.y) * kvp[5]);
  o1.z = f2bu(bfu(w1.z) * kvp[6]); o1.w = f2bu(bfu(w1.w) * kvp[7]);
  u16* dst = wob + (long)b * Dd * DIi + e;
  *(ushort4*)dst = o0;
  *(ushort4*)(dst + 4) = o1;
}

#define GLL(src, dst) \
  __builtin_amdgcn_global_load_lds((const __attribute__((address_space(1))) unsigned int*)(src), \
                                   (__attribute__((address_space(3))) unsigned int*)(dst), 16, 0, 0)

// =================== 256^2-tile 8-wave pipelined GEMM (round-9 schedule) ===================
enum { G_PROJ = 0, G_FFN1 = 2, G_FFN2 = 3, G_KV = 4 };

template<int MODE>
__global__ __launch_bounds__(512, 2) void gemm8(
    const u16* __restrict__ A, const u16* __restrict__ Bt,
    int N, int K,
    u16* __restrict__ Ybf, float* __restrict__ Yf,
    const u16* __restrict__ resb, const float* __restrict__ bias,
    float* __restrict__ nsq, const float* __restrict__ nsqIn,
    const u16* __restrict__ Kst, float* __restrict__ kvout)
{
  __shared__ u16 lds8[65536];   // 128 KB

  const int bx = blockIdx.x;
  const int by = blockIdx.y;
  const int tid  = threadIdx.x;
  const int lane = tid & 63;
  const int wid  = tid >> 6;
  const int wr = wid >> 2, wc = wid & 3;
  const int l15 = lane & 15, lg = lane >> 4;

  const long bm0 = (long)by * 256;
  const long bn0 = (long)bx * 256;
  const int NT = K >> 6;

  const int bq = (int)(bm0 >> 12);
  const u16* pA = A + bm0 * K;
  const u16* pB = Bt + bn0 * K;

  const int rowT = ((tid >> 6) << 3) | (tid & 7);
  const int cc8  = ((tid >> 3) & 7) * 8;

#define STAGE(PTR, LD, H, TT, BUFU, REGU) do {                                  \
    const u16* s0_ = (PTR) + (size_t)((H) * 128 + rowT) * (LD)                  \
                     + (size_t)(TT) * 64 + cc8;                                 \
    u16* d_ = lds8 + (BUFU) + (REGU) + (H) * 8192 + wid * 512;                  \
    GLL(s0_, d_);                                                               \
    GLL(s0_ + (size_t)64 * (LD), d_ + 4096);                                    \
  } while (0)

  const int aoff = (wr * 16384 + (l15 >> 3) * 1024 + lg * 128 + (l15 & 7) * 16) >> 1;
  const int boff = (32768 + (wc >> 1) * 16384 + (wc & 1) * 8192 +
                    (l15 >> 3) * 1024 + lg * 128 + (l15 & 7) * 16) >> 1;
#define LDA(M_, KS_, BU_) (*(const bf16x8*)(lds8 + (BU_) + aoff + (M_) * 1024 + (KS_) * 256))
#define LDB(N_, KS_, BU_) (*(const bf16x8*)(lds8 + (BU_) + boff + (N_) * 1024 + (KS_) * 256))

  f32x4 acc[8][4] = {};

  STAGE(pA, K, 0, 0, 0, 0);
  STAGE(pA, K, 1, 0, 0, 0);
  STAGE(pB, K, 0, 0, 0, 16384);
  STAGE(pB, K, 1, 0, 0, 16384);
  STAGE(pA, K, 0, 1, 32768, 0);
  asm volatile("s_waitcnt vmcnt(2)" ::: "memory");
  __builtin_amdgcn_s_barrier();

  for (int t = 0; t < NT; ++t) {
    const int bufu = (t & 1) * 32768;
    const int nbuf = bufu ^ 32768;
    bf16x8 aF[4], bF[4];

#pragma unroll
    for (int n = 0; n < 4; ++n) bF[n] = LDB(n, 0, bufu);
#pragma unroll
    for (int m = 0; m < 4; ++m) aF[m] = LDA(m, 0, bufu);
    if (t + 1 < NT) STAGE(pA, K, 1, t + 1, nbuf, 0);
    __builtin_amdgcn_s_barrier();
    __builtin_amdgcn_s_setprio(1);
#pragma unroll
    for (int m = 0; m < 4; ++m)
#pragma unroll
      for (int n = 0; n < 4; ++n)
        acc[m][n] = __builtin_amdgcn_mfma_f32_16x16x32_bf16(aF[m], bF[n], acc[m][n], 0, 0, 0);
    __builtin_amdgcn_s_setprio(0);

#pragma unroll
    for (int m = 0; m < 4; ++m) aF[m] = LDA(4 + m, 0, bufu);
    if (t + 1 < NT) STAGE(pB, K, 0, t + 1, nbuf, 16384);
    __builtin_amdgcn_s_barrier();
    __builtin_amdgcn_s_setprio(1);
#pragma unroll
    for (int m = 0; m < 4; ++m)
#pragma unroll
      for (int n = 0; n < 4; ++n)
        acc[4 + m][n] = __builtin_amdgcn_mfma_f32_16x16x32_bf16(aF[m], bF[n], acc[4 + m][n], 0, 0, 0);
    __builtin_amdgcn_s_setprio(0);

#pragma unroll
    for (int n = 0; n < 4; ++n) bF[n] = LDB(n, 1, bufu);
#pragma unroll
    for (int m = 0; m < 4; ++m) aF[m] = LDA(m, 1, bufu);
    if (t + 1 < NT) STAGE(pB, K, 1, t + 1, nbuf, 16384);
    __builtin_amdgcn_s_barrier();
    __builtin_amdgcn_s_setprio(1);
#pragma unroll
    for (int m = 0; m < 4; ++m)
#pragma unroll
      for (int n = 0; n < 4; ++n)
        acc[m][n] = __builtin_amdgcn_mfma_f32_16x16x32_bf16(aF[m], bF[n], acc[m][n], 0, 0, 0);
    __builtin_amdgcn_s_setprio(0);

#pragma unroll
    for (int m = 0; m < 4; ++m) aF[m] = LDA(4 + m, 1, bufu);
    __builtin_amdgcn_s_barrier();
    __builtin_amdgcn_s_setprio(1);
#pragma unroll
    for (int m = 0; m < 4; ++m)
#pragma unroll
      for (int n = 0; n < 4; ++n)
        acc[4 + m][n] = __builtin_amdgcn_mfma_f32_16x16x32_bf16(aF[m], bF[n], acc[4 + m][n], 0, 0, 0);
    __builtin_amdgcn_s_setprio(0);

    if (t + 1 < NT) {
      __builtin_amdgcn_s_barrier();
      if (t + 2 < NT) {
        STAGE(pA, K, 0, t + 2, bufu, 0);
        asm volatile("s_waitcnt vmcnt(2)" ::: "memory");
      } else {
        asm volatile("s_waitcnt vmcnt(0)" ::: "memory");
      }
      __builtin_amdgcn_s_barrier();
    }
  }

  // =================== epilogue ===================
  if constexpr (MODE == G_KV) {
    __syncthreads();
#pragma unroll
    for (int i = 0; i < 16; ++i) {
      const int r_ = i * 16 + wid * 2 + (lane >> 5);
      const int c_ = (lane & 31) ^ (r_ & 15);
      const u16* src = Kst + (size_t)(bm0 + r_) * N + bn0 + c_ * 8;
      u16* d_ = lds8 + i * 4096 + wid * 512;
      GLL(src, d_);
    }
    asm volatile("s_waitcnt vmcnt(0)" ::: "memory");
    __builtin_amdgcn_s_barrier();

    const int col4 = wc * 64 + l15;
    float cs[4] = {0.f, 0.f, 0.f, 0.f};
#pragma unroll
    for (int m = 0; m < 8; ++m) {
      const long row0g = bm0 + wr * 128 + m * 16 + lg * 4;
      float rn4[4];
#pragma unroll
      for (int r = 0; r < 4; ++r)
        rn4[r] = 1.f / fmaxf(sqrtf(nsqIn[row0g + r]), 1e-12f);
#pragma unroll
      for (int n = 0; n < 4; ++n) {
        const int col = col4 + n * 16;
#pragma unroll
        for (int r = 0; r < 4; ++r) {
          const int krow = wr * 128 + m * 16 + lg * 4 + r;
          const int byte_ = krow * 512 + (((col >> 3) ^ (krow & 15)) << 4) + (col & 7) * 2;
          const float kvl = bfu(*(const u16*)((const char*)lds8 + byte_));
          cs[n] += kvl * rn4[r] * acc[m][n][r];
        }
      }
    }
#pragma unroll
    for (int n = 0; n < 4; ++n) {
      cs[n] += __shfl_xor(cs[n], 16, 64);
      cs[n] += __shfl_xor(cs[n], 32, 64);
    }
    if (lane < 16) {
#pragma unroll
      for (int n = 0; n < 4; ++n) {
        const long col = bn0 + wc * 64 + n * 16 + l15;
        atomicAdd(&kvout[(long)bq * DIi + col], cs[n]);
      }
    }
  } else if constexpr (MODE == G_PROJ) {
    float sk[32];
#pragma unroll
    for (int i = 0; i < 32; ++i) sk[i] = 0.f;
#pragma unroll
    for (int m = 0; m < 8; ++m) {
      const long row0 = bm0 + wr * 128 + m * 16 + lg * 4;
#pragma unroll
      for (int n = 0; n < 4; ++n) {
        const long col = bn0 + wc * 64 + n * 16 + l15;
#pragma unroll
        for (int r = 0; r < 4; ++r) {
          const float v = acc[m][n][r];
          Ybf[(row0 + r) * N + col] = f2bu(v);
          sk[m * 4 + r] += v * v;
        }
      }
    }
#pragma unroll
    for (int i = 0; i < 32; ++i) {
#pragma unroll
      for (int off = 1; off < 16; off <<= 1)
        sk[i] += __shfl_xor(sk[i], off, 64);
    }
    if (l15 == 0) {
#pragma unroll
      for (int m = 0; m < 8; ++m)
#pragma unroll
        for (int r = 0; r < 4; ++r)
          atomicAdd(&nsq[bm0 + wr * 128 + m * 16 + lg * 4 + r], sk[m * 4 + r]);
    }
  } else {
#pragma unroll
    for (int m = 0; m < 8; ++m) {
      const long row0 = bm0 + wr * 128 + m * 16 + lg * 4;
#pragma unroll
      for (int n = 0; n < 4; ++n) {
        const long col = bn0 + wc * 64 + n * 16 + l15;
#pragma unroll
        for (int r = 0; r < 4; ++r) {
          const long idx = (row0 + r) * N + col;
          const float v = acc[m][n][r];
          if constexpr (MODE == G_FFN1) {
            float o = v + bias[col];
            o = o > 0.f ? o : 0.f;
            Ybf[idx] = f2bu(o);
          } else {  // G_FFN2
            Yf[idx] = v + bias[col] + bfu(resb[idx]);
          }
        }
      }
    }
  }
#undef STAGE
#undef LDA
#undef LDB
}

// ====== small-GEMM: 9x [512,2048]@[2048,512] -> transposed bf16 [512][512] ======
// z=0: G = wqb@wqb^T -> Gt ; z=1..8: U_b = wqb@wob_b^T -> Ut[b] (stored [d'][d])
__global__ __launch_bounds__(256) void mega_small(
    const u16* __restrict__ wqb, const u16* __restrict__ wob,
    u16* __restrict__ Gt, u16* __restrict__ Ut)
{
  __shared__ u16 As[4096];   // 8 KB
  __shared__ u16 Bs[4096];   // 8 KB
  const int K = DIi;
  const int z = blockIdx.z;
  const u16* Bt = (z == 0) ? wqb : wob + (size_t)(z - 1) * Dd * DIi;
  u16* Ct = (z == 0) ? Gt : Ut + (size_t)(z - 1) * Dd * Dd;

  const int tid = threadIdx.x, lane = tid & 63, w = tid >> 6;
  const int wr = w >> 1, wc = w & 1;
  const int l15 = lane & 15, lg = lane >> 4;
  const long bm0 = (long)blockIdx.y * 128;
  const long bn0 = (long)blockIdx.x * 128;

  const int c0 = tid, c1 = tid + 256;
  const u16* aS0 = wqb + (bm0 + (c0 >> 2)) * K + (c0 & 3) * 8;
  const u16* aS1 = wqb + (bm0 + (c1 >> 2)) * K + (c1 & 3) * 8;
  const u16* bS0 = Bt  + (bn0 + (c0 >> 2)) * K + (c0 & 3) * 8;
  const u16* bS1 = Bt  + (bn0 + (c1 >> 2)) * K + (c1 & 3) * 8;
  u16* aD0 = As + w * 512;
  u16* aD1 = As + 2048 + w * 512;
  u16* bD0 = Bs + w * 512;
  u16* bD1 = Bs + 2048 + w * 512;

  f32x4 acc[4][4] = {};

  for (int k0 = 0; k0 < K; k0 += 32) {
    GLL(aS0 + k0, aD0);
    GLL(aS1 + k0, aD1);
    GLL(bS0 + k0, bD0);
    GLL(bS1 + k0, bD1);
    __syncthreads();
    bf16x8 af[4], bfv[4];
#pragma unroll
    for (int m = 0; m < 4; ++m)
      af[m] = *(const bf16x8*)(As + (wr * 64 + m * 16 + l15) * 32 + lg * 8);
#pragma unroll
    for (int n = 0; n < 4; ++n)
      bfv[n] = *(const bf16x8*)(Bs + (wc * 64 + n * 16 + l15) * 32 + lg * 8);
#pragma unroll
    for (int m = 0; m < 4; ++m)
#pragma unroll
      for (int n = 0; n < 4; ++n)
        acc[m][n] = __builtin_amdgcn_mfma_f32_16x16x32_bf16(af[m], bfv[n], acc[m][n], 0, 0, 0);
    __syncthreads();
  }

  // transposed store: Ct[col][row]  (rows r=0..3 consecutive -> ushort4)
#pragma unroll
  for (int m = 0; m < 4; ++m) {
    const int row0 = (int)bm0 + wr * 64 + m * 16 + lg * 4;
#pragma unroll
    for (int n = 0; n < 4; ++n) {
      const int col = (int)bn0 + wc * 64 + n * 16 + l15;
      ushort4 o;
      o.x = f2bu(acc[m][n][0]); o.y = f2bu(acc[m][n][1]);
      o.z = f2bu(acc[m][n][2]); o.w = f2bu(acc[m][n][3]);
      *(ushort4*)(Ct + (size_t)col * Dd + row0) = o;
    }
  }
}

// ====== mega_nx: M x 512 GEMM (K=512) with x-restage epilogue ======
// MODE 0 (NQ):  acc = x@G tile; nqsq[row] += sum_col acc*x  (atomics)
// MODE 1 (AWO): acc = x@U_b tile; attnb = bf16(acc*rsqrt(nqsq) + x)
template<int MODE>
__global__ __launch_bounds__(256) void mega_nx(
    const u16* __restrict__ xb, const u16* __restrict__ Gt, const u16* __restrict__ Ut,
    float* __restrict__ nqsq, u16* __restrict__ attnb)
{
  __shared__ u16 As[4096];    // 8 KB
  __shared__ u16 Bs[4096];    // 8 KB
  __shared__ u16 xs[16384];   // 32 KB x-tile restage
  const int K = Dd, N = Dd;

  const int tid = threadIdx.x, lane = tid & 63, w = tid >> 6;
  const int wr = w >> 1, wc = w & 1;
  const int l15 = lane & 15, lg = lane >> 4;
  const long bm0 = (long)blockIdx.y * 128;
  const long bn0 = (long)blockIdx.x * 128;
  const int bq = (int)(bm0 >> 12);
  const u16* Bt = (MODE == 0) ? Gt : Ut + (size_t)bq * Dd * Dd;

  const int c0 = tid, c1 = tid + 256;
  const u16* aS0 = xb + (bm0 + (c0 >> 2)) * K + (c0 & 3) * 8;
  const u16* aS1 = xb + (bm0 + (c1 >> 2)) * K + (c1 & 3) * 8;
  const u16* bS0 = Bt + (bn0 + (c0 >> 2)) * K + (c0 & 3) * 8;
  const u16* bS1 = Bt + (bn0 + (c1 >> 2)) * K + (c1 & 3) * 8;
  u16* aD0 = As + w * 512;
  u16* aD1 = As + 2048 + w * 512;
  u16* bD0 = Bs + w * 512;
  u16* bD1 = Bs + 2048 + w * 512;

  f32x4 acc[4][4] = {};

  for (int k0 = 0; k0 < K; k0 += 32) {
    GLL(aS0 + k0, aD0);
    GLL(aS1 + k0, aD1);
    GLL(bS0 + k0, bD0);
    GLL(bS1 + k0, bD1);
    __syncthreads();
    bf16x8 af[4], bfv[4];
#pragma unroll
    for (int m = 0; m < 4; ++m)
      af[m] = *(const bf16x8*)(As + (wr * 64 + m * 16 + l15) * 32 + lg * 8);
#pragma unroll
    for (int n = 0; n < 4; ++n)
      bfv[n] = *(const bf16x8*)(Bs + (wc * 64 + n * 16 + l15) * 32 + lg * 8);
#pragma unroll
    for (int m = 0; m < 4; ++m)
#pragma unroll
      for (int n = 0; n < 4; ++n)
        acc[m][n] = __builtin_amdgcn_mfma_f32_16x16x32_bf16(af[m], bfv[n], acc[m][n], 0, 0, 0);
    __syncthreads();
  }

  // restage block's x tile [128 rows x 128 cols] with slot-XOR swizzle
#pragma unroll
  for (int i = 0; i < 8; ++i) {
    const int c = i * 256 + tid;
    const int rowL = c >> 4;
    const int srcslot = (c & 15) ^ (rowL & 15);
    const u16* src = xb + (size_t)(bm0 + rowL) * Dd + bn0 + srcslot * 8;
    GLL(src, xs + i * 2048 + w * 512);
  }
  asm volatile("s_waitcnt vmcnt(0)" ::: "memory");
  __builtin_amdgcn_s_barrier();

#define XV(RL, CL) bfu(xs[(RL) * 128 + ((((CL) >> 3) ^ ((RL) & 15)) << 3) + ((CL) & 7)])

  if constexpr (MODE == 0) {
    float sk[16];
#pragma unroll
    for (int i = 0; i < 16; ++i) sk[i] = 0.f;
#pragma unroll
    for (int m = 0; m < 4; ++m) {
#pragma unroll
      for (int n = 0; n < 4; ++n) {
        const int colL = wc * 64 + n * 16 + l15;
#pragma unroll
        for (int r = 0; r < 4; ++r) {
          const int rowL = wr * 64 + m * 16 + lg * 4 + r;
          sk[m * 4 + r] += acc[m][n][r] * XV(rowL, colL);
        }
      }
    }
#pragma unroll
    for (int i = 0; i < 16; ++i) {
#pragma unroll
      for (int off = 1; off < 16; off <<= 1)
        sk[i] += __shfl_xor(sk[i], off, 64);
    }
    if (l15 == 0) {
#pragma unroll
      for (int m = 0; m < 4; ++m)
#pragma unroll
        for (int r = 0; r < 4; ++r)
          atomicAdd(&nqsq[bm0 + wr * 64 + m * 16 + lg * 4 + r], sk[m * 4 + r]);
    }
  } else {
#pragma unroll
    for (int m = 0; m < 4; ++m) {
      const long row0 = bm0 + wr * 64 + m * 16 + lg * 4;
      float rq[4];
#pragma unroll
      for (int r = 0; r < 4; ++r)
        rq[r] = 1.f / fmaxf(sqrtf(fmaxf(nqsq[row0 + r], 0.f)), 1e-12f);
#pragma unroll
      for (int n = 0; n < 4; ++n) {
        const int colL = wc * 64 + n * 16 + l15;
#pragma unroll
        for (int r = 0; r < 4; ++r) {
          const int rowL = wr * 64 + m * 16 + lg * 4 + r;
          attnb[(row0 + r) * N + bn0 + colL] = f2bu(acc[m][n][r] * rq[r] + XV(rowL, colL));
        }
      }
    }
  }
#undef XV
}

extern "C" void kernel_launch(void* const* d_in, const int* in_sizes, int n_in,
                              void* d_out, int out_size, void* d_ws, size_t ws_size,
                              hipStream_t stream) {
  const float* x  = (const float*)d_in[0];
  const float* wq = (const float*)d_in[1];
  const float* wk = (const float*)d_in[2];
  const float* wv = (const float*)d_in[3];
  const float* wo = (const float*)d_in[4];
  const float* w1 = (const float*)d_in[5];
  const float* b1 = (const float*)d_in[6];
  const float* w2 = (const float*)d_in[7];
  const float* b2 = (const float*)d_in[8];
  float* out = (float*)d_out;

  char* p = (char*)d_ws;
  auto take = [&](size_t bytes) {
    char* r = p; p += (bytes + 255) & ~(size_t)255; return r;
  };
  u16*   xb    = (u16*)take((size_t)Mm * Dd * 2);        // 33.5 MB
  u16*   wkT   = (u16*)take((size_t)DIi * Dd * 2);
  u16*   wvT   = (u16*)take((size_t)DIi * Dd * 2);
  u16*   woT   = (u16*)take((size_t)Dd * DIi * 2);
  u16*   w1T   = (u16*)take((size_t)DIi * Dd * 2);
  u16*   w2T   = (u16*)take((size_t)Dd * DIi * 2);
  u16*   wqb   = (u16*)take((size_t)Dd * DIi * 2);       // wq bf16 [d][e]
  u16*   wob   = (u16*)take((size_t)Bb * Dd * DIi * 2);  // 16.8 MB
  u16*   Gt    = (u16*)take((size_t)Dd * Dd * 2);        // 0.5 MB
  u16*   Ut    = (u16*)take((size_t)Bb * Dd * Dd * 2);   // 4.2 MB
  u16*   buf1  = (u16*)take((size_t)Mm * DIi * 2);       // K, then h (134 MB)
  u16*   attnb = (u16*)take((size_t)Mm * Dd * 2);        // 33.5 MB
  float* nksq  = (float*)take((size_t)Mm * 4);           // contiguous with next two
  float* nqsq  = (float*)take((size_t)Mm * 4);
  float* kvp   = (float*)take((size_t)Bb * DIi * 4);
  (void)in_sizes; (void)n_in; (void)out_size; (void)ws_size;

  // fused prep: zero(nksq..kvp) + conv x + 5 transposes + conv wq
  prep<<<8512, 256, 0, stream>>>(x, xb, wk, wv, w1, wo, w2, wq,
                                 wkT, wvT, w1T, woT, w2T, wqb, nksq);

  // K = x@wk -> buf1 (bf16) + nksq
  gemm8<G_PROJ><<<dim3(DIi / 256, Mm / 256), 512, 0, stream>>>(
      xb, wkT, DIi, Dd, buf1, nullptr, nullptr, nullptr, nksq, nullptr,
      nullptr, nullptr);

  // kv[b,e]: V = x@wv tiles + LDS-staged K re-read + 1/||k||
  gemm8<G_KV><<<dim3(DIi / 256, Mm / 256), 512, 0, stream>>>(
      xb, wvT, DIi, Dd, nullptr, nullptr, nullptr, nullptr, nullptr, nksq,
      buf1, kvp);

  // wob[b] = woT * kv[b]
  build_wob<<<dim3((Dd * DIi / 8 + 255) / 256, Bb), 256, 0, stream>>>(woT, kvp, wob);

  // G = wqb@wqb^T -> Gt ; U_b = wqb@wob_b^T -> Ut (transposed bf16)
  mega_small<<<dim3(4, 4, 9), 256, 0, stream>>>(wqb, wob, Gt, Ut);

  // nqsq[m] = rowdot(x@G, x)
  mega_nx<0><<<dim3(4, Mm / 128), 256, 0, stream>>>(xb, Gt, nullptr, nqsq, nullptr);

  // attn = (x@U_b)*rsqrt(nqsq) + x -> attnb
  mega_nx<1><<<dim3(4, Mm / 128), 256, 0, stream>>>(xb, nullptr, Ut, nqsq, attnb);

  // h = relu(attn @ w1 + b1) -> buf1
  gemm8<G_FFN1><<<dim3(DIi / 256, Mm / 256), 512, 0, stream>>>(
      attnb, w1T, DIi, Dd, buf1, nullptr, nullptr, b1, nullptr, nullptr,
      nullptr, nullptr);

  // out = h @ w2 + b2 + attn
  gemm8<G_FFN2><<<dim3(Dd / 256, Mm / 256), 512, 0, stream>>>(
      buf1, w2T, Dd, DIi, nullptr, out, attnb, b2, nullptr, nullptr,
      nullptr, nullptr);
}